// Round 4
// baseline (4621.730 us; speedup 1.0000x reference)
//
#include <hip/hip_runtime.h>
#include <hip/hip_bf16.h>

#define N_NODES 100000
#define N_EDGES 1600000

static __device__ __forceinline__ float bf2f(__hip_bfloat16 x) { return __bfloat162float(x); }
static __device__ __forceinline__ float us2f(unsigned short u) {
    union { unsigned int i; float f; } cv; cv.i = ((unsigned int)u) << 16; return cv.f;
}

// ---------------- prep: Cmat = inv(I - A^T); M = A^T*Cmat; Wcomb = fold(M, W_mean); AT = A^T ----
__global__ __launch_bounds__(256) void k_prep(const float* __restrict__ A,
                                              const float* __restrict__ Wm,
                                              float* __restrict__ Wcomb,
                                              float* __restrict__ AT) {
    __shared__ float Af[32][32];
    __shared__ float aug[32][65];
    __shared__ float Cm[32][32];
    __shared__ float Mm[32][32];
    __shared__ float fac[32];
    __shared__ float pivinv_s;
    int tid = threadIdx.x;
    for (int i = tid; i < 1024; i += 256) Af[i >> 5][i & 31] = A[i];
    __syncthreads();
    // augmented [B | I], B = I - A^T  (B[r][c] = delta - A[c][r])
    for (int i = tid; i < 2048; i += 256) {
        int r = i >> 6, c = i & 63;
        float v;
        if (c < 32) v = (r == c ? 1.0f : 0.0f) - Af[c][r];
        else        v = ((c - 32) == r ? 1.0f : 0.0f);
        aug[r][c] = v;
    }
    __syncthreads();
    for (int k = 0; k < 32; ++k) {
        if (tid == 0) pivinv_s = 1.0f / aug[k][k];
        __syncthreads();
        float pivinv = pivinv_s;
        if (tid < 64) aug[k][tid] *= pivinv;
        __syncthreads();
        if (tid < 32) fac[tid] = aug[tid][k];
        __syncthreads();
        for (int i = tid; i < 2048; i += 256) {
            int r = i >> 6, c = i & 63;
            if (r != k) aug[r][c] -= fac[r] * aug[k][c];
        }
        __syncthreads();
    }
    for (int i = tid; i < 1024; i += 256) Cm[i >> 5][i & 31] = aug[i >> 5][32 + (i & 31)];
    __syncthreads();
    // M[c][j] = sum_k A^T[c][k]*Cm[k][j] = sum_k Af[k][c]*Cm[k][j];  AT[c][j] = Af[j][c]
    for (int i = tid; i < 1024; i += 256) {
        int c = i >> 5, j = i & 31;
        float s = 0.f;
        for (int k = 0; k < 32; ++k) s += Af[k][c] * Cm[k][j];
        Mm[c][j] = s;
        AT[i] = Af[j][c];
    }
    __syncthreads();
    // Wcomb[h][c*4+d] = sum_j Mm[c][j] * Wm[h*128 + j*4 + d]
    for (int i = tid; i < 16384; i += 256) {
        int h = i >> 7, m = i & 127;
        int c = m >> 2, d = m & 3;
        float s = 0.f;
        for (int j = 0; j < 32; ++j) s += Mm[c][j] * Wm[h * 128 + j * 4 + d];
        Wcomb[i] = s;
    }
}

// ---------------- spmm1: S1[dst,0:32] += val * X[src,0:32]  (8 lanes/edge, float4 loads) -----
__global__ __launch_bounds__(256) void k_spmm1(const int* __restrict__ esrc,
                                               const int* __restrict__ edst,
                                               const float* __restrict__ evalv,
                                               const float* __restrict__ X,
                                               float* __restrict__ S1) {
    int sub = threadIdx.x & 7;             // lane within edge (4 cols each)
    int el  = threadIdx.x >> 3;            // 0..31 edge within block
    int e = blockIdx.x * 32 + el;
    int src = esrc[e], dst = edst[e];
    float v = evalv[e];
    float4 x4 = ((const float4*)(X + src * 32))[sub];
    float* s = &S1[dst * 32 + sub * 4];
    unsafeAtomicAdd(s + 0, v * x4.x);
    unsafeAtomicAdd(s + 1, v * x4.y);
    unsafeAtomicAdd(s + 2, v * x4.z);
    unsafeAtomicAdd(s + 3, v * x4.w);
}

// ---------------- gemm1: hidden = bf16(relu(S1 @ W_base)), [N,32]x[32,128] -------------------
__global__ __launch_bounds__(256) void k_gemm1(const float* __restrict__ S1,
                                               const float* __restrict__ Wb,
                                               __hip_bfloat16* __restrict__ hidden) {
    __shared__ float Wb_s[32][128];
    __shared__ float St[32][33];
    int tid = threadIdx.x;
    int j = tid & 127, half = tid >> 7;
    int n0 = blockIdx.x * 32;
    for (int i = tid; i < 4096; i += 256) Wb_s[i >> 7][i & 127] = Wb[i];
    for (int i = tid; i < 1024; i += 256) St[i >> 5][i & 31] = S1[n0 * 32 + i];
    __syncthreads();
    float acc[16];
    #pragma unroll
    for (int i = 0; i < 16; ++i) acc[i] = 0.f;
    #pragma unroll
    for (int k = 0; k < 32; ++k) {
        float wv = Wb_s[k][j];
        #pragma unroll
        for (int i = 0; i < 16; ++i) acc[i] += St[half + 2 * i][k] * wv;
    }
    #pragma unroll
    for (int i = 0; i < 16; ++i) {
        float v = acc[i];
        hidden[(n0 + half + 2 * i) * 128 + j] = __float2bfloat16(v > 0.f ? v : 0.f);
    }
}

// ---------------- spmm2: S2[dst,0:128] += val * hidden[src,0:128] (32 lanes/edge, ushort4) ----
__global__ __launch_bounds__(256) void k_spmm2(const int* __restrict__ esrc,
                                               const int* __restrict__ edst,
                                               const float* __restrict__ evalv,
                                               const __hip_bfloat16* __restrict__ hidden,
                                               float* __restrict__ S2) {
    int lane = threadIdx.x & 31;           // 4 cols each
    int el   = threadIdx.x >> 5;           // 0..7 edge within block
    int e = blockIdx.x * 8 + el;
    int src = esrc[e], dst = edst[e];
    float v = evalv[e];
    const ushort4* hp = (const ushort4*)(hidden + src * 128);
    ushort4 h4 = hp[lane];
    float* s = &S2[dst * 128 + lane * 4];
    unsafeAtomicAdd(s + 0, v * us2f(h4.x));
    unsafeAtomicAdd(s + 1, v * us2f(h4.y));
    unsafeAtomicAdd(s + 2, v * us2f(h4.z));
    unsafeAtomicAdd(s + 3, v * us2f(h4.w));
}

// ---------------- gemm2 (IN-PLACE on S2): masked = S2 @ Wcomb, [N,128]x[128,128] -------------
// Safe in-place: each block reads only rows n0..n0+31 (all K chunks) before writing those rows.
__global__ __launch_bounds__(256) void k_gemm2(float* __restrict__ S2,
                                               const float* __restrict__ Wc) {
    __shared__ float Wt[32][128];
    __shared__ float St[32][33];
    int tid = threadIdx.x;
    int j = tid & 127, half = tid >> 7;
    int n0 = blockIdx.x * 32;
    float acc[16];
    #pragma unroll
    for (int i = 0; i < 16; ++i) acc[i] = 0.f;
    for (int kb = 0; kb < 4; ++kb) {
        for (int i = tid; i < 4096; i += 256) Wt[i >> 7][i & 127] = Wc[(kb * 32 + (i >> 7)) * 128 + (i & 127)];
        for (int i = tid; i < 1024; i += 256) St[i >> 5][i & 31] = S2[(n0 + (i >> 5)) * 128 + kb * 32 + (i & 31)];
        __syncthreads();
        #pragma unroll
        for (int k = 0; k < 32; ++k) {
            float wv = Wt[k][j];
            #pragma unroll
            for (int i = 0; i < 16; ++i) acc[i] += St[half + 2 * i][k] * wv;
        }
        __syncthreads();
    }
    #pragma unroll
    for (int i = 0; i < 16; ++i) S2[(n0 + half + 2 * i) * 128 + j] = acc[i];
}

// ---------------- fused per-node: MLPs + noise + rec_x + label head --------------------------
__global__ __launch_bounds__(256) void k_node(const float* __restrict__ masked,
                                              const float* __restrict__ noise,
                                              const float* __restrict__ label,
                                              const float* __restrict__ Wz1,
                                              const float* __restrict__ bz1,
                                              const float* __restrict__ Wz2,
                                              const float* __restrict__ bz2,
                                              const float* __restrict__ Wl1,
                                              const float* __restrict__ bl1,
                                              const float* __restrict__ Wl2,
                                              const float* __restrict__ bl2,
                                              const float* __restrict__ Wrec,
                                              const float* __restrict__ brec,
                                              const float* __restrict__ AT,
                                              float* __restrict__ out) {
    __shared__ float Wz1s[4096];                   // [c][d][g], stride 128
    __shared__ float Wz2s[32 * 130];               // [c][g][d], padded row stride 130
    __shared__ __hip_bfloat16 Wrecs[4096];         // [h][o] (bf16 to save LDS)
    __shared__ float bz1s[32 * 33];                // padded 33
    __shared__ float Wl1s[32 * 33], bl1s[32 * 33], Wl2s[32 * 33], ATs[32 * 33];
    __shared__ float bz2s[128], bl2s[32], brecs[32];
    __shared__ float mk[2][128];
    __shared__ float hzs[2][32 * 33];
    __shared__ float zs[2][128];
    int tid = threadIdx.x;
    for (int i = tid; i < 4096; i += 256) {
        Wz1s[i] = Wz1[i];
        Wz2s[(i >> 7) * 130 + (i & 127)] = Wz2[i];
        Wrecs[i] = __float2bfloat16(Wrec[i]);
    }
    for (int i = tid; i < 1024; i += 256) {
        int p = (i >> 5) * 33 + (i & 31);
        bz1s[p] = bz1[i];
        Wl1s[p] = Wl1[i];
        bl1s[p] = bl1[i];
        Wl2s[p] = Wl2[i];
        ATs[p]  = AT[i];
    }
    if (tid < 128) bz2s[tid] = bz2[tid];
    if (tid < 32) { bl2s[tid] = bl2[tid]; brecs[tid] = brec[tid]; }
    __syncthreads();

    int nl = tid >> 7, tl = tid & 127;
    int n0 = blockIdx.x * 32;
    for (int it = 0; it < 16; ++it) {
        int n = n0 + it * 2 + nl;
        mk[nl][tl] = masked[n * 128 + tl];
        __syncthreads();
        // phase 1: hz[c][g] = elu(bz1 + sum_d mk[c*4+d]*Wz1[c][d][g]) ; thread = (g, c-quad)
        {
            int g = tl & 31, cq = tl >> 5;
            #pragma unroll
            for (int ci = 0; ci < 8; ++ci) {
                int c = cq * 8 + ci;
                float m0 = mk[nl][c * 4 + 0];
                float m1 = mk[nl][c * 4 + 1];
                float m2 = mk[nl][c * 4 + 2];
                float m3 = mk[nl][c * 4 + 3];
                float v = bz1s[c * 33 + g]
                        + m0 * Wz1s[c * 128 + g]
                        + m1 * Wz1s[c * 128 + 32 + g]
                        + m2 * Wz1s[c * 128 + 64 + g]
                        + m3 * Wz1s[c * 128 + 96 + g];
                hzs[nl][c * 33 + g] = v > 0.f ? v : expm1f(v);
            }
        }
        __syncthreads();
        // phase 2: mz2[c][d] + noise -> z ; thread = (c,d) = tl
        {
            int c = tl >> 2, d = tl & 3;
            float s = bz2s[tl];
            #pragma unroll
            for (int g2 = 0; g2 < 32; ++g2)
                s += hzs[nl][c * 33 + g2] * Wz2s[c * 130 + g2 * 4 + d];
            float z = s + 0.03162277660168379f * noise[n * 128 + tl];
            zs[nl][tl] = z;
        }
        __syncthreads();
        // phase 3a: rec_x (threads 0..31); 3b: label head (threads 32..63)
        if (tl < 32) {
            int o = tl;
            float r = brecs[o];
            #pragma unroll
            for (int h = 0; h < 128; ++h) r += zs[nl][h] * bf2f(Wrecs[h * 32 + o]);
            out[n * 32 + o] = r;
        } else if (tl < 64) {
            int c = tl - 32;
            float ml = 0.f;
            #pragma unroll
            for (int k = 0; k < 32; ++k) ml += ATs[c * 33 + k] * label[n * 32 + k];
            float p = bl2s[c];
            #pragma unroll
            for (int g = 0; g < 32; ++g) {
                float h = ml * Wl1s[c * 33 + g] + bl1s[c * 33 + g];
                h = h > 0.f ? h : expm1f(h);
                p += h * Wl2s[c * 33 + g];
            }
            out[N_NODES * 32 + n * 32 + c] = p;
        }
        __syncthreads();
    }
}

extern "C" void kernel_launch(void* const* d_in, const int* in_sizes, int n_in,
                              void* d_out, int out_size, void* d_ws, size_t ws_size,
                              hipStream_t stream) {
    // Inputs are FLOAT32 (reference setup_inputs uses jnp.float32 throughout; confirmed:
    // bf16 reads gave NaN, f32 reads give finite values). Output is FLOAT32 too —
    // reference computes/returns f32; the "(bf16, ...)" in the test message is
    // hard-coded template text, and threshold = 2% * max|ref| exactly (no bf16 floor).
    const float* X      = (const float*)d_in[0];
    const float* label  = (const float*)d_in[1];
    const float* evalv  = (const float*)d_in[2];
    const float* noise  = (const float*)d_in[3];
    const float* W_base = (const float*)d_in[4];
    const float* W_mean = (const float*)d_in[5];
    // d_in[6] = W_logstd : dead code in the reference (result discarded)
    const float* A      = (const float*)d_in[7];
    const float* Wz1    = (const float*)d_in[8];
    const float* bz1    = (const float*)d_in[9];
    const float* Wz2    = (const float*)d_in[10];
    const float* bz2    = (const float*)d_in[11];
    const float* Wl1    = (const float*)d_in[12];
    const float* bl1    = (const float*)d_in[13];
    const float* Wl2    = (const float*)d_in[14];
    const float* bl2    = (const float*)d_in[15];
    const float* Wrec   = (const float*)d_in[16];
    const float* brec   = (const float*)d_in[17];
    const int* esrc = (const int*)d_in[18];
    const int* edst = (const int*)d_in[19];
    float* out = (float*)d_out;

    char* ws = (char*)d_ws;
    // Compact layout, total ~73.3 MB:
    //   Wcomb  @ 0         : 16384 f32 (64 KB)
    //   AT     @ 65536     : 1024 f32 (4 KB)
    //   hidden @ 69632     : N*128 bf16 (25.6 MB)
    //   S2     @ 25669632  : N*128 f32 (51.2 MB)
    //   S1 ALIASES S2's first 12.8 MB (S1 dead before S2 is zeroed)
    float*          Wcomb  = (float*)(ws);
    float*          AT     = (float*)(ws + 65536);
    __hip_bfloat16* hidden = (__hip_bfloat16*)(ws + 69632);
    float*          S2     = (float*)(ws + 69632 + 25600000);
    float*          S1     = S2;

    hipMemsetAsync(S1, 0, N_NODES * 32 * sizeof(float), stream);   // 12.8 MB
    k_prep<<<1, 256, 0, stream>>>(A, W_mean, Wcomb, AT);
    k_spmm1<<<N_EDGES / 32, 256, 0, stream>>>(esrc, edst, evalv, X, S1);
    k_gemm1<<<N_NODES / 32, 256, 0, stream>>>(S1, W_base, hidden);
    hipMemsetAsync(S2, 0, N_NODES * 128 * sizeof(float), stream);  // 51.2 MB (S1 now dead)
    k_spmm2<<<N_EDGES / 8, 256, 0, stream>>>(esrc, edst, evalv, hidden, S2);
    k_gemm2<<<N_NODES / 32, 256, 0, stream>>>(S2, Wcomb);
    k_node<<<N_NODES / 32, 256, 0, stream>>>(S2, noise, label,
                                             Wz1, bz1, Wz2, bz2, Wl1, bl1, Wl2, bl2,
                                             Wrec, brec, AT, out);
}

// Round 5
// 1932.368 us; speedup vs baseline: 2.3917x; 2.3917x over previous
//
#include <hip/hip_runtime.h>
#include <hip/hip_bf16.h>

#define N_NODES 100000
#define N_EDGES 1600000

static __device__ __forceinline__ float bf2f(__hip_bfloat16 x) { return __bfloat162float(x); }
static __device__ __forceinline__ float us2f(unsigned short u) {
    union { unsigned int i; float f; } cv; cv.i = ((unsigned int)u) << 16; return cv.f;
}
static __device__ __forceinline__ unsigned short f2us(float f) {
    __hip_bfloat16 b = __float2bfloat16(f);
    union { __hip_bfloat16 b; unsigned short u; } cv; cv.b = b; return cv.u;
}

// ---------------- prep: Cmat = inv(I - A^T); M = A^T*Cmat; Wcomb = fold(M, W_mean); AT = A^T ----
__global__ __launch_bounds__(256) void k_prep(const float* __restrict__ A,
                                              const float* __restrict__ Wm,
                                              float* __restrict__ Wcomb,
                                              float* __restrict__ AT) {
    __shared__ float Af[32][32];
    __shared__ float aug[32][65];
    __shared__ float Cm[32][32];
    __shared__ float Mm[32][32];
    __shared__ float fac[32];
    __shared__ float pivinv_s;
    int tid = threadIdx.x;
    for (int i = tid; i < 1024; i += 256) Af[i >> 5][i & 31] = A[i];
    __syncthreads();
    for (int i = tid; i < 2048; i += 256) {
        int r = i >> 6, c = i & 63;
        float v;
        if (c < 32) v = (r == c ? 1.0f : 0.0f) - Af[c][r];
        else        v = ((c - 32) == r ? 1.0f : 0.0f);
        aug[r][c] = v;
    }
    __syncthreads();
    for (int k = 0; k < 32; ++k) {
        if (tid == 0) pivinv_s = 1.0f / aug[k][k];
        __syncthreads();
        float pivinv = pivinv_s;
        if (tid < 64) aug[k][tid] *= pivinv;
        __syncthreads();
        if (tid < 32) fac[tid] = aug[tid][k];
        __syncthreads();
        for (int i = tid; i < 2048; i += 256) {
            int r = i >> 6, c = i & 63;
            if (r != k) aug[r][c] -= fac[r] * aug[k][c];
        }
        __syncthreads();
    }
    for (int i = tid; i < 1024; i += 256) Cm[i >> 5][i & 31] = aug[i >> 5][32 + (i & 31)];
    __syncthreads();
    for (int i = tid; i < 1024; i += 256) {
        int c = i >> 5, j = i & 31;
        float s = 0.f;
        for (int k = 0; k < 32; ++k) s += Af[k][c] * Cm[k][j];
        Mm[c][j] = s;
        AT[i] = Af[j][c];
    }
    __syncthreads();
    for (int i = tid; i < 16384; i += 256) {
        int h = i >> 7, m = i & 127;
        int c = m >> 2, d = m & 3;
        float s = 0.f;
        for (int j = 0; j < 32; ++j) s += Mm[c][j] * Wm[h * 128 + j * 4 + d];
        Wcomb[i] = s;
    }
}

// ---------------- CSR build: histogram -> scan -> scatter ------------------------------------
__global__ __launch_bounds__(256) void k_hist(const int* __restrict__ edst,
                                              unsigned int* __restrict__ deg) {
    int e = blockIdx.x * 256 + threadIdx.x;
    atomicAdd(&deg[edst[e]], 1u);
}

// single block, 1024 threads: exclusive scan of deg[0..N) -> row_start, cursor
__global__ __launch_bounds__(1024) void k_scan(const unsigned int* __restrict__ deg,
                                               unsigned int* __restrict__ row_start,
                                               unsigned int* __restrict__ cursor) {
    __shared__ unsigned int sums[1024];
    const int CH = 98;  // 1024*98 = 100352 >= 100000
    int tid = threadIdx.x;
    int base = tid * CH;
    unsigned int local = 0;
    for (int i = 0; i < CH; ++i) {
        int idx = base + i;
        if (idx < N_NODES) local += deg[idx];
    }
    sums[tid] = local;
    __syncthreads();
    for (int off = 1; off < 1024; off <<= 1) {
        unsigned int v = (tid >= off) ? sums[tid - off] : 0u;
        __syncthreads();
        sums[tid] += v;
        __syncthreads();
    }
    unsigned int run = sums[tid] - local;   // exclusive prefix of this chunk
    for (int i = 0; i < CH; ++i) {
        int idx = base + i;
        if (idx < N_NODES) {
            row_start[idx] = run;
            cursor[idx] = run;
            run += deg[idx];
        }
    }
    if (tid == 0) row_start[N_NODES] = N_EDGES;
}

__global__ __launch_bounds__(256) void k_scatter(const int* __restrict__ esrc,
                                                 const int* __restrict__ edst,
                                                 const float* __restrict__ evalv,
                                                 unsigned int* __restrict__ cursor,
                                                 int* __restrict__ src_sorted,
                                                 float* __restrict__ val_sorted) {
    int e = blockIdx.x * 256 + threadIdx.x;
    unsigned int p = atomicAdd(&cursor[edst[e]], 1u);
    src_sorted[p] = esrc[e];
    val_sorted[p] = evalv[e];
}

// ---------------- enc1 (fused spmm1+gemm1): hidden = bf16(relu((A.X) @ W_base)) --------------
// 256 threads, 16 rows/block; group g (32 lanes) gathers rows n0+g and n0+8+g.
__global__ __launch_bounds__(256) void k_enc1(const unsigned int* __restrict__ row_start,
                                              const int* __restrict__ src_sorted,
                                              const float* __restrict__ val_sorted,
                                              const float* __restrict__ X,
                                              const float* __restrict__ Wb,
                                              __hip_bfloat16* __restrict__ hidden) {
    __shared__ float Wb_s[4096];      // [k][j] 32x128
    __shared__ float S1s[16 * 33];    // padded
    int tid = threadIdx.x;
    int lane = tid & 31, g = tid >> 5;
    int n0 = blockIdx.x * 16;
    for (int i = tid; i < 1024; i += 256)
        ((float4*)Wb_s)[i] = ((const float4*)Wb)[i];
    // gather phase: 2 rows per group
    #pragma unroll
    for (int rr = 0; rr < 2; ++rr) {
        int r = g + rr * 8;
        int n = n0 + r;
        unsigned int s0 = row_start[n], s1 = row_start[n + 1];
        float acc = 0.f;
        for (unsigned int i = s0; i < s1; ++i) {
            float v = val_sorted[i];
            int s = src_sorted[i];
            acc += v * X[s * 32 + lane];
        }
        S1s[r * 33 + lane] = acc;
    }
    __syncthreads();
    // gemm phase: out (16 rows x 128 cols), thread -> rows g,g+8, cols lane*4..+3
    float4 a0 = {0, 0, 0, 0}, a1 = {0, 0, 0, 0};
    #pragma unroll
    for (int k = 0; k < 32; ++k) {
        float s0 = S1s[g * 33 + k];
        float s1 = S1s[(g + 8) * 33 + k];
        float4 w = *(const float4*)&Wb_s[k * 128 + lane * 4];
        a0.x += s0 * w.x; a0.y += s0 * w.y; a0.z += s0 * w.z; a0.w += s0 * w.w;
        a1.x += s1 * w.x; a1.y += s1 * w.y; a1.z += s1 * w.z; a1.w += s1 * w.w;
    }
    ushort4 o0, o1;
    o0.x = f2us(fmaxf(a0.x, 0.f)); o0.y = f2us(fmaxf(a0.y, 0.f));
    o0.z = f2us(fmaxf(a0.z, 0.f)); o0.w = f2us(fmaxf(a0.w, 0.f));
    o1.x = f2us(fmaxf(a1.x, 0.f)); o1.y = f2us(fmaxf(a1.y, 0.f));
    o1.z = f2us(fmaxf(a1.z, 0.f)); o1.w = f2us(fmaxf(a1.w, 0.f));
    ((ushort4*)(hidden + (n0 + g) * 128))[lane] = o0;
    ((ushort4*)(hidden + (n0 + g + 8) * 128))[lane] = o1;
}

// ---------------- dec (fused spmm2+gemm2): masked = bf16((A.hidden) @ Wcomb) -----------------
// 256 threads, 16 rows/block; Wcomb staged in LDS (64KB f32).
__global__ __launch_bounds__(256) void k_dec(const unsigned int* __restrict__ row_start,
                                             const int* __restrict__ src_sorted,
                                             const float* __restrict__ val_sorted,
                                             const __hip_bfloat16* __restrict__ hidden,
                                             const float* __restrict__ Wc,
                                             __hip_bfloat16* __restrict__ masked) {
    __shared__ float Wc_s[16384];     // [k][j] 128x128
    __shared__ float S2s[16 * 132];   // padded, float4-aligned rows
    int tid = threadIdx.x;
    int lane = tid & 31, g = tid >> 5;
    int n0 = blockIdx.x * 16;
    for (int i = tid; i < 4096; i += 256)
        ((float4*)Wc_s)[i] = ((const float4*)Wc)[i];
    // gather phase: 2 rows per group; lane covers cols lane*4..+3 (ushort4 loads)
    #pragma unroll
    for (int rr = 0; rr < 2; ++rr) {
        int r = g + rr * 8;
        int n = n0 + r;
        unsigned int s0 = row_start[n], s1 = row_start[n + 1];
        float4 acc = {0, 0, 0, 0};
        for (unsigned int i = s0; i < s1; ++i) {
            float v = val_sorted[i];
            int s = src_sorted[i];
            ushort4 h4 = ((const ushort4*)(hidden + s * 128))[lane];
            acc.x += v * us2f(h4.x);
            acc.y += v * us2f(h4.y);
            acc.z += v * us2f(h4.z);
            acc.w += v * us2f(h4.w);
        }
        *(float4*)&S2s[r * 132 + lane * 4] = acc;
    }
    __syncthreads();
    // gemm phase: thread -> rows g,g+8, cols lane*4..+3; k-loop in quads (b128 LDS reads)
    float4 a0 = {0, 0, 0, 0}, a1 = {0, 0, 0, 0};
    for (int k4 = 0; k4 < 128; k4 += 4) {
        float4 s0 = *(const float4*)&S2s[g * 132 + k4];
        float4 s1 = *(const float4*)&S2s[(g + 8) * 132 + k4];
        #pragma unroll
        for (int kk = 0; kk < 4; ++kk) {
            float v0 = (&s0.x)[kk];
            float v1 = (&s1.x)[kk];
            float4 w = *(const float4*)&Wc_s[(k4 + kk) * 128 + lane * 4];
            a0.x += v0 * w.x; a0.y += v0 * w.y; a0.z += v0 * w.z; a0.w += v0 * w.w;
            a1.x += v1 * w.x; a1.y += v1 * w.y; a1.z += v1 * w.z; a1.w += v1 * w.w;
        }
    }
    ushort4 o0, o1;
    o0.x = f2us(a0.x); o0.y = f2us(a0.y); o0.z = f2us(a0.z); o0.w = f2us(a0.w);
    o1.x = f2us(a1.x); o1.y = f2us(a1.y); o1.z = f2us(a1.z); o1.w = f2us(a1.w);
    ((ushort4*)(masked + (n0 + g) * 128))[lane] = o0;
    ((ushort4*)(masked + (n0 + g + 8) * 128))[lane] = o1;
}

// ---------------- fused per-node: MLPs + noise + rec_x + label head --------------------------
__global__ __launch_bounds__(256) void k_node(const __hip_bfloat16* __restrict__ masked,
                                              const float* __restrict__ noise,
                                              const float* __restrict__ label,
                                              const float* __restrict__ Wz1,
                                              const float* __restrict__ bz1,
                                              const float* __restrict__ Wz2,
                                              const float* __restrict__ bz2,
                                              const float* __restrict__ Wl1,
                                              const float* __restrict__ bl1,
                                              const float* __restrict__ Wl2,
                                              const float* __restrict__ bl2,
                                              const float* __restrict__ Wrec,
                                              const float* __restrict__ brec,
                                              const float* __restrict__ AT,
                                              float* __restrict__ out) {
    __shared__ float Wz1s[4096];                   // [c][d][g], stride 128
    __shared__ float Wz2s[32 * 130];               // [c][g][d], padded row stride 130
    __shared__ __hip_bfloat16 Wrecs[4096];         // [h][o] (bf16 to save LDS)
    __shared__ float bz1s[32 * 33];
    __shared__ float Wl1s[32 * 33], bl1s[32 * 33], Wl2s[32 * 33], ATs[32 * 33];
    __shared__ float bz2s[128], bl2s[32], brecs[32];
    __shared__ float mk[2][128];
    __shared__ float hzs[2][32 * 33];
    __shared__ float zs[2][128];
    int tid = threadIdx.x;
    for (int i = tid; i < 4096; i += 256) {
        Wz1s[i] = Wz1[i];
        Wz2s[(i >> 7) * 130 + (i & 127)] = Wz2[i];
        Wrecs[i] = __float2bfloat16(Wrec[i]);
    }
    for (int i = tid; i < 1024; i += 256) {
        int p = (i >> 5) * 33 + (i & 31);
        bz1s[p] = bz1[i];
        Wl1s[p] = Wl1[i];
        bl1s[p] = bl1[i];
        Wl2s[p] = Wl2[i];
        ATs[p]  = AT[i];
    }
    if (tid < 128) bz2s[tid] = bz2[tid];
    if (tid < 32) { bl2s[tid] = bl2[tid]; brecs[tid] = brec[tid]; }
    __syncthreads();

    int nl = tid >> 7, tl = tid & 127;
    int n0 = blockIdx.x * 32;
    for (int it = 0; it < 16; ++it) {
        int n = n0 + it * 2 + nl;
        mk[nl][tl] = bf2f(masked[n * 128 + tl]);
        __syncthreads();
        {
            int g = tl & 31, cq = tl >> 5;
            #pragma unroll
            for (int ci = 0; ci < 8; ++ci) {
                int c = cq * 8 + ci;
                float m0 = mk[nl][c * 4 + 0];
                float m1 = mk[nl][c * 4 + 1];
                float m2 = mk[nl][c * 4 + 2];
                float m3 = mk[nl][c * 4 + 3];
                float v = bz1s[c * 33 + g]
                        + m0 * Wz1s[c * 128 + g]
                        + m1 * Wz1s[c * 128 + 32 + g]
                        + m2 * Wz1s[c * 128 + 64 + g]
                        + m3 * Wz1s[c * 128 + 96 + g];
                hzs[nl][c * 33 + g] = v > 0.f ? v : expm1f(v);
            }
        }
        __syncthreads();
        {
            int c = tl >> 2, d = tl & 3;
            float s = bz2s[tl];
            #pragma unroll
            for (int g2 = 0; g2 < 32; ++g2)
                s += hzs[nl][c * 33 + g2] * Wz2s[c * 130 + g2 * 4 + d];
            float z = s + 0.03162277660168379f * noise[n * 128 + tl];
            zs[nl][tl] = z;
        }
        __syncthreads();
        if (tl < 32) {
            int o = tl;
            float r = brecs[o];
            #pragma unroll
            for (int h = 0; h < 128; ++h) r += zs[nl][h] * bf2f(Wrecs[h * 32 + o]);
            out[n * 32 + o] = r;
        } else if (tl < 64) {
            int c = tl - 32;
            float ml = 0.f;
            #pragma unroll
            for (int k = 0; k < 32; ++k) ml += ATs[c * 33 + k] * label[n * 32 + k];
            float p = bl2s[c];
            #pragma unroll
            for (int g = 0; g < 32; ++g) {
                float h = ml * Wl1s[c * 33 + g] + bl1s[c * 33 + g];
                h = h > 0.f ? h : expm1f(h);
                p += h * Wl2s[c * 33 + g];
            }
            out[N_NODES * 32 + n * 32 + c] = p;
        }
        __syncthreads();
    }
}

extern "C" void kernel_launch(void* const* d_in, const int* in_sizes, int n_in,
                              void* d_out, int out_size, void* d_ws, size_t ws_size,
                              hipStream_t stream) {
    // Inputs f32 (verified round 3/4), edge indices int32, output f32 (verified round 4).
    const float* X      = (const float*)d_in[0];
    const float* label  = (const float*)d_in[1];
    const float* evalv  = (const float*)d_in[2];
    const float* noise  = (const float*)d_in[3];
    const float* W_base = (const float*)d_in[4];
    const float* W_mean = (const float*)d_in[5];
    // d_in[6] = W_logstd : dead code in the reference
    const float* A      = (const float*)d_in[7];
    const float* Wz1    = (const float*)d_in[8];
    const float* bz1    = (const float*)d_in[9];
    const float* Wz2    = (const float*)d_in[10];
    const float* bz2    = (const float*)d_in[11];
    const float* Wl1    = (const float*)d_in[12];
    const float* bl1    = (const float*)d_in[13];
    const float* Wl2    = (const float*)d_in[14];
    const float* bl2    = (const float*)d_in[15];
    const float* Wrec   = (const float*)d_in[16];
    const float* brec   = (const float*)d_in[17];
    const int* esrc = (const int*)d_in[18];
    const int* edst = (const int*)d_in[19];
    float* out = (float*)d_out;

    char* ws = (char*)d_ws;
    // Layout (~65.3 MB total):
    float*          Wcomb      = (float*)(ws);                        // 64 KB
    float*          AT         = (float*)(ws + 65536);                // 4 KB
    unsigned int*   deg        = (unsigned int*)(ws + 69632);         // 400 KB
    unsigned int*   row_start  = (unsigned int*)(ws + 469760);        // 400004 B (N+1)
    unsigned int*   cursor     = (unsigned int*)(ws + 869888);        // 400 KB
    int*            src_sorted = (int*)(ws + 1269888);                // 6.4 MB
    float*          val_sorted = (float*)(ws + 7669888);              // 6.4 MB
    __hip_bfloat16* hidden     = (__hip_bfloat16*)(ws + 14069888);    // 25.6 MB
    __hip_bfloat16* masked     = (__hip_bfloat16*)(ws + 39669888);    // 25.6 MB

    hipMemsetAsync(deg, 0, N_NODES * sizeof(unsigned int), stream);
    k_prep<<<1, 256, 0, stream>>>(A, W_mean, Wcomb, AT);
    k_hist<<<N_EDGES / 256, 256, 0, stream>>>(edst, deg);
    k_scan<<<1, 1024, 0, stream>>>(deg, row_start, cursor);
    k_scatter<<<N_EDGES / 256, 256, 0, stream>>>(esrc, edst, evalv, cursor, src_sorted, val_sorted);
    k_enc1<<<N_NODES / 16, 256, 0, stream>>>(row_start, src_sorted, val_sorted, X, W_base, hidden);
    k_dec<<<N_NODES / 16, 256, 0, stream>>>(row_start, src_sorted, val_sorted, hidden, Wcomb, masked);
    k_node<<<N_NODES / 32, 256, 0, stream>>>(masked, noise, label,
                                             Wz1, bz1, Wz2, bz2, Wl1, bl1, Wl2, bl2,
                                             Wrec, brec, AT, out);
}

// Round 6
// 1349.539 us; speedup vs baseline: 3.4247x; 1.4319x over previous
//
#include <hip/hip_runtime.h>
#include <hip/hip_bf16.h>

#define N_NODES 100000
#define N_EDGES 1600000

static __device__ __forceinline__ float bf2f(__hip_bfloat16 x) { return __bfloat162float(x); }
static __device__ __forceinline__ float us2f(unsigned short u) {
    union { unsigned int i; float f; } cv; cv.i = ((unsigned int)u) << 16; return cv.f;
}
static __device__ __forceinline__ unsigned short f2us(float f) {
    __hip_bfloat16 b = __float2bfloat16(f);
    union { __hip_bfloat16 b; unsigned short u; } cv; cv.b = b; return cv.u;
}
static __device__ __forceinline__ float elu_fast(float v) {
    return v > 0.f ? v : (__expf(v) - 1.0f);
}

// ---------------- prep: Cmat = inv(I - A^T); M = A^T*Cmat; Wcomb = fold(M, W_mean); AT = A^T ----
__global__ __launch_bounds__(256) void k_prep(const float* __restrict__ A,
                                              const float* __restrict__ Wm,
                                              float* __restrict__ Wcomb,
                                              float* __restrict__ AT) {
    __shared__ float Af[32][32];
    __shared__ float aug[32][65];
    __shared__ float Cm[32][32];
    __shared__ float Mm[32][32];
    __shared__ float fac[32];
    __shared__ float pivinv_s;
    int tid = threadIdx.x;
    for (int i = tid; i < 1024; i += 256) Af[i >> 5][i & 31] = A[i];
    __syncthreads();
    for (int i = tid; i < 2048; i += 256) {
        int r = i >> 6, c = i & 63;
        float v;
        if (c < 32) v = (r == c ? 1.0f : 0.0f) - Af[c][r];
        else        v = ((c - 32) == r ? 1.0f : 0.0f);
        aug[r][c] = v;
    }
    __syncthreads();
    for (int k = 0; k < 32; ++k) {
        if (tid == 0) pivinv_s = 1.0f / aug[k][k];
        __syncthreads();
        float pivinv = pivinv_s;
        if (tid < 64) aug[k][tid] *= pivinv;
        __syncthreads();
        if (tid < 32) fac[tid] = aug[tid][k];
        __syncthreads();
        for (int i = tid; i < 2048; i += 256) {
            int r = i >> 6, c = i & 63;
            if (r != k) aug[r][c] -= fac[r] * aug[k][c];
        }
        __syncthreads();
    }
    for (int i = tid; i < 1024; i += 256) Cm[i >> 5][i & 31] = aug[i >> 5][32 + (i & 31)];
    __syncthreads();
    for (int i = tid; i < 1024; i += 256) {
        int c = i >> 5, j = i & 31;
        float s = 0.f;
        for (int k = 0; k < 32; ++k) s += Af[k][c] * Cm[k][j];
        Mm[c][j] = s;
        AT[i] = Af[j][c];
    }
    __syncthreads();
    for (int i = tid; i < 16384; i += 256) {
        int h = i >> 7, m = i & 127;
        int c = m >> 2, d = m & 3;
        float s = 0.f;
        for (int j = 0; j < 32; ++j) s += Mm[c][j] * Wm[h * 128 + j * 4 + d];
        Wcomb[i] = s;
    }
}

// ---------------- CSR build: histogram -> scan -> scatter ------------------------------------
__global__ __launch_bounds__(256) void k_hist(const int* __restrict__ edst,
                                              unsigned int* __restrict__ deg) {
    int e = blockIdx.x * 256 + threadIdx.x;
    atomicAdd(&deg[edst[e]], 1u);
}

__global__ __launch_bounds__(1024) void k_scan(const unsigned int* __restrict__ deg,
                                               unsigned int* __restrict__ row_start,
                                               unsigned int* __restrict__ cursor) {
    __shared__ unsigned int sums[1024];
    const int CH = 98;  // 1024*98 >= 100000
    int tid = threadIdx.x;
    int base = tid * CH;
    unsigned int local = 0;
    for (int i = 0; i < CH; ++i) {
        int idx = base + i;
        if (idx < N_NODES) local += deg[idx];
    }
    sums[tid] = local;
    __syncthreads();
    for (int off = 1; off < 1024; off <<= 1) {
        unsigned int v = (tid >= off) ? sums[tid - off] : 0u;
        __syncthreads();
        sums[tid] += v;
        __syncthreads();
    }
    unsigned int run = sums[tid] - local;
    for (int i = 0; i < CH; ++i) {
        int idx = base + i;
        if (idx < N_NODES) {
            row_start[idx] = run;
            cursor[idx] = run;
            run += deg[idx];
        }
    }
    if (tid == 0) row_start[N_NODES] = N_EDGES;
}

__global__ __launch_bounds__(256) void k_scatter(const int* __restrict__ esrc,
                                                 const int* __restrict__ edst,
                                                 const float* __restrict__ evalv,
                                                 unsigned int* __restrict__ cursor,
                                                 int* __restrict__ src_sorted,
                                                 float* __restrict__ val_sorted) {
    int e = blockIdx.x * 256 + threadIdx.x;
    unsigned int p = atomicAdd(&cursor[edst[e]], 1u);
    src_sorted[p] = esrc[e];
    val_sorted[p] = evalv[e];
}

// ---------------- enc1 (fused spmm1+gemm1): hidden = bf16(relu((A.X) @ W_base)) --------------
__global__ __launch_bounds__(256) void k_enc1(const unsigned int* __restrict__ row_start,
                                              const int* __restrict__ src_sorted,
                                              const float* __restrict__ val_sorted,
                                              const float* __restrict__ X,
                                              const float* __restrict__ Wb,
                                              __hip_bfloat16* __restrict__ hidden) {
    __shared__ float Wb_s[4096];      // [k][j] 32x128
    __shared__ float S1s[16 * 33];
    int tid = threadIdx.x;
    int lane = tid & 31, g = tid >> 5;
    int n0 = blockIdx.x * 16;
    for (int i = tid; i < 1024; i += 256)
        ((float4*)Wb_s)[i] = ((const float4*)Wb)[i];
    #pragma unroll
    for (int rr = 0; rr < 2; ++rr) {
        int r = g + rr * 8;
        int n = n0 + r;
        unsigned int s0 = row_start[n], s1 = row_start[n + 1];
        float acc = 0.f;
        for (unsigned int i = s0; i < s1; ++i) {
            float v = val_sorted[i];
            int s = src_sorted[i];
            acc += v * X[s * 32 + lane];
        }
        S1s[r * 33 + lane] = acc;
    }
    __syncthreads();
    float4 a0 = {0, 0, 0, 0}, a1 = {0, 0, 0, 0};
    #pragma unroll
    for (int k = 0; k < 32; ++k) {
        float s0 = S1s[g * 33 + k];
        float s1 = S1s[(g + 8) * 33 + k];
        float4 w = *(const float4*)&Wb_s[k * 128 + lane * 4];
        a0.x += s0 * w.x; a0.y += s0 * w.y; a0.z += s0 * w.z; a0.w += s0 * w.w;
        a1.x += s1 * w.x; a1.y += s1 * w.y; a1.z += s1 * w.z; a1.w += s1 * w.w;
    }
    ushort4 o0, o1;
    o0.x = f2us(fmaxf(a0.x, 0.f)); o0.y = f2us(fmaxf(a0.y, 0.f));
    o0.z = f2us(fmaxf(a0.z, 0.f)); o0.w = f2us(fmaxf(a0.w, 0.f));
    o1.x = f2us(fmaxf(a1.x, 0.f)); o1.y = f2us(fmaxf(a1.y, 0.f));
    o1.z = f2us(fmaxf(a1.z, 0.f)); o1.w = f2us(fmaxf(a1.w, 0.f));
    ((ushort4*)(hidden + (n0 + g) * 128))[lane] = o0;
    ((ushort4*)(hidden + (n0 + g + 8) * 128))[lane] = o1;
}

// ---------------- dec (fused spmm2+gemm2): masked_T[j][n] = bf16((A.hidden) @ Wcomb)^T -------
__global__ __launch_bounds__(256) void k_dec(const unsigned int* __restrict__ row_start,
                                             const int* __restrict__ src_sorted,
                                             const float* __restrict__ val_sorted,
                                             const __hip_bfloat16* __restrict__ hidden,
                                             const float* __restrict__ Wc,
                                             unsigned short* __restrict__ masked_T) {
    __shared__ float Wc_s[16384];     // 64 KB
    __shared__ float S2s[16 * 132];
    __shared__ unsigned short Tt[16 * 132];   // transpose tile
    int tid = threadIdx.x;
    int lane = tid & 31, g = tid >> 5;
    int n0 = blockIdx.x * 16;
    for (int i = tid; i < 4096; i += 256)
        ((float4*)Wc_s)[i] = ((const float4*)Wc)[i];
    #pragma unroll
    for (int rr = 0; rr < 2; ++rr) {
        int r = g + rr * 8;
        int n = n0 + r;
        unsigned int s0 = row_start[n], s1 = row_start[n + 1];
        float4 acc = {0, 0, 0, 0};
        for (unsigned int i = s0; i < s1; ++i) {
            float v = val_sorted[i];
            int s = src_sorted[i];
            ushort4 h4 = ((const ushort4*)(hidden + s * 128))[lane];
            acc.x += v * us2f(h4.x);
            acc.y += v * us2f(h4.y);
            acc.z += v * us2f(h4.z);
            acc.w += v * us2f(h4.w);
        }
        *(float4*)&S2s[r * 132 + lane * 4] = acc;
    }
    __syncthreads();
    float4 a0 = {0, 0, 0, 0}, a1 = {0, 0, 0, 0};
    for (int k4 = 0; k4 < 128; k4 += 4) {
        float4 s0 = *(const float4*)&S2s[g * 132 + k4];
        float4 s1 = *(const float4*)&S2s[(g + 8) * 132 + k4];
        #pragma unroll
        for (int kk = 0; kk < 4; ++kk) {
            float v0 = (&s0.x)[kk];
            float v1 = (&s1.x)[kk];
            float4 w = *(const float4*)&Wc_s[(k4 + kk) * 128 + lane * 4];
            a0.x += v0 * w.x; a0.y += v0 * w.y; a0.z += v0 * w.z; a0.w += v0 * w.w;
            a1.x += v1 * w.x; a1.y += v1 * w.y; a1.z += v1 * w.z; a1.w += v1 * w.w;
        }
    }
    ushort4 o0, o1;
    o0.x = f2us(a0.x); o0.y = f2us(a0.y); o0.z = f2us(a0.z); o0.w = f2us(a0.w);
    o1.x = f2us(a1.x); o1.y = f2us(a1.y); o1.z = f2us(a1.z); o1.w = f2us(a1.w);
    *(ushort4*)&Tt[g * 132 + lane * 4] = o0;
    *(ushort4*)&Tt[(g + 8) * 132 + lane * 4] = o1;
    __syncthreads();
    // write transposed: thread -> col j = tid>>1, node-segment seg = tid&1 (8 nodes, 16B)
    int j = tid >> 1, seg = tid & 1;
    union { uint4 u4; unsigned short us[8]; } pk;
    #pragma unroll
    for (int r = 0; r < 8; ++r) pk.us[r] = Tt[(seg * 8 + r) * 132 + j];
    *(uint4*)(masked_T + (size_t)j * N_NODES + n0 + seg * 8) = pk.u4;
}

// ---------------- noise head: rec_noise = sqrt(lambda) * (noise @ Wrec), [N,128]x[128,32] ----
__global__ __launch_bounds__(256) void k_noise(const float* __restrict__ noise,
                                               const float* __restrict__ Wrec,
                                               float* __restrict__ rec_noise) {
    __shared__ float Wr[4096];        // [k][o] 128x32, 16 KB
    __shared__ float Ns[64 * 132];    // 64 rows padded, 33.8 KB
    int tid = threadIdx.x;
    int n0 = blockIdx.x * 64;
    for (int i = tid; i < 1024; i += 256)
        ((float4*)Wr)[i] = ((const float4*)Wrec)[i];
    for (int i = tid; i < 2048; i += 256) {
        int row = i >> 5, c4 = i & 31;
        int n = n0 + row;
        float4 v = (n < N_NODES) ? ((const float4*)(noise + (size_t)n * 128))[c4]
                                 : make_float4(0.f, 0.f, 0.f, 0.f);
        *(float4*)&Ns[row * 132 + c4 * 4] = v;
    }
    __syncthreads();
    int r = tid >> 2, q = (tid & 3) * 8;     // row, col-octet
    float4 acc0 = {0, 0, 0, 0}, acc1 = {0, 0, 0, 0};
    for (int k = 0; k < 128; ++k) {
        float nv = Ns[r * 132 + k];
        float4 w0 = *(const float4*)&Wr[k * 32 + q];
        float4 w1 = *(const float4*)&Wr[k * 32 + q + 4];
        acc0.x += nv * w0.x; acc0.y += nv * w0.y; acc0.z += nv * w0.z; acc0.w += nv * w0.w;
        acc1.x += nv * w1.x; acc1.y += nv * w1.y; acc1.z += nv * w1.z; acc1.w += nv * w1.w;
    }
    const float SQ = 0.03162277660168379f;
    acc0.x *= SQ; acc0.y *= SQ; acc0.z *= SQ; acc0.w *= SQ;
    acc1.x *= SQ; acc1.y *= SQ; acc1.z *= SQ; acc1.w *= SQ;
    int n = n0 + r;
    if (n < N_NODES) {
        ((float4*)(rec_noise + (size_t)n * 32 + q))[0] = acc0;
        ((float4*)(rec_noise + (size_t)n * 32 + q + 4))[0] = acc1;
    }
}

// ---------------- nodez: per-lane node MLP + rec_x head --------------------------------------
// one lane per node; all LDS weight reads are wave-uniform broadcasts (conflict-free)
__global__ __launch_bounds__(256) void k_nodez(const unsigned short* __restrict__ masked_T,
                                               const float* __restrict__ rec_noise,
                                               const float* __restrict__ Wz1,
                                               const float* __restrict__ bz1,
                                               const float* __restrict__ Wz2,
                                               const float* __restrict__ bz2,
                                               const float* __restrict__ Wrec,
                                               const float* __restrict__ brec,
                                               float* __restrict__ out) {
    __shared__ float Wz1s[4096];   // [c][d][g]
    __shared__ float Wz2s[4096];   // [c][g][d]
    __shared__ float Wrecs[4096];  // [h][o]
    __shared__ float bz1s[1024];   // [c][g]
    __shared__ float bz2s[128];    // [c][d]
    __shared__ float brecs[32];
    int tid = threadIdx.x;
    for (int i = tid; i < 4096; i += 256) {
        Wz1s[i] = Wz1[i];
        Wz2s[i] = Wz2[i];
        Wrecs[i] = Wrec[i];
    }
    for (int i = tid; i < 1024; i += 256) bz1s[i] = bz1[i];
    if (tid < 128) bz2s[tid] = bz2[tid];
    if (tid < 32) brecs[tid] = brec[tid];
    __syncthreads();

    int n = blockIdx.x * 256 + tid;
    bool ok = n < N_NODES;
    int nn = ok ? n : (N_NODES - 1);

    float rec[32];
    #pragma unroll
    for (int q = 0; q < 8; ++q) {
        float4 rv = ((const float4*)(rec_noise + (size_t)nn * 32))[q];
        rec[q * 4 + 0] = brecs[q * 4 + 0] + rv.x;
        rec[q * 4 + 1] = brecs[q * 4 + 1] + rv.y;
        rec[q * 4 + 2] = brecs[q * 4 + 2] + rv.z;
        rec[q * 4 + 3] = brecs[q * 4 + 3] + rv.w;
    }

    for (int c = 0; c < 32; ++c) {
        float m0 = us2f(masked_T[(size_t)(c * 4 + 0) * N_NODES + nn]);
        float m1 = us2f(masked_T[(size_t)(c * 4 + 1) * N_NODES + nn]);
        float m2 = us2f(masked_T[(size_t)(c * 4 + 2) * N_NODES + nn]);
        float m3 = us2f(masked_T[(size_t)(c * 4 + 3) * N_NODES + nn]);
        float z0 = bz2s[c * 4 + 0], z1 = bz2s[c * 4 + 1];
        float z2 = bz2s[c * 4 + 2], z3 = bz2s[c * 4 + 3];
        #pragma unroll
        for (int g = 0; g < 32; ++g) {
            float v = bz1s[c * 32 + g]
                    + m0 * Wz1s[c * 128 + g]
                    + m1 * Wz1s[c * 128 + 32 + g]
                    + m2 * Wz1s[c * 128 + 64 + g]
                    + m3 * Wz1s[c * 128 + 96 + g];
            v = elu_fast(v);
            z0 += v * Wz2s[c * 128 + g * 4 + 0];
            z1 += v * Wz2s[c * 128 + g * 4 + 1];
            z2 += v * Wz2s[c * 128 + g * 4 + 2];
            z3 += v * Wz2s[c * 128 + g * 4 + 3];
        }
        #pragma unroll
        for (int o = 0; o < 32; ++o) {
            rec[o] += z0 * Wrecs[(c * 4 + 0) * 32 + o]
                    + z1 * Wrecs[(c * 4 + 1) * 32 + o]
                    + z2 * Wrecs[(c * 4 + 2) * 32 + o]
                    + z3 * Wrecs[(c * 4 + 3) * 32 + o];
        }
    }
    if (ok) {
        #pragma unroll
        for (int q = 0; q < 8; ++q) {
            float4 v = {rec[q * 4 + 0], rec[q * 4 + 1], rec[q * 4 + 2], rec[q * 4 + 3]};
            ((float4*)(out + (size_t)n * 32))[q] = v;
        }
    }
}

// ---------------- label head: pred = MLP_c(AT@label), one lane per node ----------------------
__global__ __launch_bounds__(256) void k_label(const float* __restrict__ label,
                                               const float* __restrict__ AT,
                                               const float* __restrict__ Wl1,
                                               const float* __restrict__ bl1,
                                               const float* __restrict__ Wl2,
                                               const float* __restrict__ bl2,
                                               float* __restrict__ out) {
    __shared__ float ATs[1024], Wl1s[1024], bl1s[1024], Wl2s[1024], bl2s[32];
    int tid = threadIdx.x;
    for (int i = tid; i < 1024; i += 256) {
        ATs[i] = AT[i];
        Wl1s[i] = Wl1[i];
        bl1s[i] = bl1[i];
        Wl2s[i] = Wl2[i];
    }
    if (tid < 32) bl2s[tid] = bl2[tid];
    __syncthreads();

    int n = blockIdx.x * 256 + tid;
    bool ok = n < N_NODES;
    int nn = ok ? n : (N_NODES - 1);

    float lab[32];
    #pragma unroll
    for (int q = 0; q < 8; ++q) {
        float4 lv = ((const float4*)(label + (size_t)nn * 32))[q];
        lab[q * 4 + 0] = lv.x; lab[q * 4 + 1] = lv.y;
        lab[q * 4 + 2] = lv.z; lab[q * 4 + 3] = lv.w;
    }
    float pred[32];
    for (int c = 0; c < 32; ++c) {
        float ml = 0.f;
        #pragma unroll
        for (int k = 0; k < 32; ++k) ml += ATs[c * 32 + k] * lab[k];
        float p = bl2s[c];
        #pragma unroll
        for (int g = 0; g < 32; ++g) {
            float h = elu_fast(ml * Wl1s[c * 32 + g] + bl1s[c * 32 + g]);
            p += h * Wl2s[c * 32 + g];
        }
        pred[c] = p;
    }
    if (ok) {
        #pragma unroll
        for (int q = 0; q < 8; ++q) {
            float4 v = {pred[q * 4 + 0], pred[q * 4 + 1], pred[q * 4 + 2], pred[q * 4 + 3]};
            ((float4*)(out + (size_t)N_NODES * 32 + (size_t)n * 32))[q] = v;
        }
    }
}

extern "C" void kernel_launch(void* const* d_in, const int* in_sizes, int n_in,
                              void* d_out, int out_size, void* d_ws, size_t ws_size,
                              hipStream_t stream) {
    // Inputs f32 (verified), edge indices int32, output f32 (verified round 4).
    const float* X      = (const float*)d_in[0];
    const float* label  = (const float*)d_in[1];
    const float* evalv  = (const float*)d_in[2];
    const float* noise  = (const float*)d_in[3];
    const float* W_base = (const float*)d_in[4];
    const float* W_mean = (const float*)d_in[5];
    // d_in[6] = W_logstd : dead code in the reference
    const float* A      = (const float*)d_in[7];
    const float* Wz1    = (const float*)d_in[8];
    const float* bz1    = (const float*)d_in[9];
    const float* Wz2    = (const float*)d_in[10];
    const float* bz2    = (const float*)d_in[11];
    const float* Wl1    = (const float*)d_in[12];
    const float* bl1    = (const float*)d_in[13];
    const float* Wl2    = (const float*)d_in[14];
    const float* bl2    = (const float*)d_in[15];
    const float* Wrec   = (const float*)d_in[16];
    const float* brec   = (const float*)d_in[17];
    const int* esrc = (const int*)d_in[18];
    const int* edst = (const int*)d_in[19];
    float* out = (float*)d_out;

    char* ws = (char*)d_ws;
    // Layout (~65.3 MB total, same footprint as round 5):
    float*          Wcomb      = (float*)(ws);                        // 64 KB
    float*          AT         = (float*)(ws + 65536);                // 4 KB
    unsigned int*   deg        = (unsigned int*)(ws + 69632);         // 400 KB
    unsigned int*   row_start  = (unsigned int*)(ws + 469760);        // N+1
    unsigned int*   cursor     = (unsigned int*)(ws + 869888);        // 400 KB
    int*            src_sorted = (int*)(ws + 1269888);                // 6.4 MB
    float*          val_sorted = (float*)(ws + 7669888);              // 6.4 MB
    __hip_bfloat16* hidden     = (__hip_bfloat16*)(ws + 14069888);    // 25.6 MB
    unsigned short* masked_T   = (unsigned short*)(ws + 39669888);    // 25.6 MB
    // rec_noise ALIASES hidden (hidden dead after k_dec; k_noise runs after k_dec)
    float*          rec_noise  = (float*)(ws + 14069888);             // 12.8 MB

    hipMemsetAsync(deg, 0, N_NODES * sizeof(unsigned int), stream);
    k_prep<<<1, 256, 0, stream>>>(A, W_mean, Wcomb, AT);
    k_hist<<<N_EDGES / 256, 256, 0, stream>>>(edst, deg);
    k_scan<<<1, 1024, 0, stream>>>(deg, row_start, cursor);
    k_scatter<<<N_EDGES / 256, 256, 0, stream>>>(esrc, edst, evalv, cursor, src_sorted, val_sorted);
    k_enc1<<<N_NODES / 16, 256, 0, stream>>>(row_start, src_sorted, val_sorted, X, W_base, hidden);
    k_dec<<<N_NODES / 16, 256, 0, stream>>>(row_start, src_sorted, val_sorted, hidden, Wcomb, masked_T);
    k_noise<<<(N_NODES + 63) / 64, 256, 0, stream>>>(noise, Wrec, rec_noise);
    k_nodez<<<(N_NODES + 255) / 256, 256, 0, stream>>>(masked_T, rec_noise,
                                                       Wz1, bz1, Wz2, bz2, Wrec, brec, out);
    k_label<<<(N_NODES + 255) / 256, 256, 0, stream>>>(label, AT, Wl1, bl1, Wl2, bl2, out);
}

// Round 7
// 801.929 us; speedup vs baseline: 5.7633x; 1.6829x over previous
//
#include <hip/hip_runtime.h>
#include <hip/hip_bf16.h>

#define N_NODES 100000
#define N_EDGES 1600000

static __device__ __forceinline__ float us2f(unsigned short u) {
    union { unsigned int i; float f; } cv; cv.i = ((unsigned int)u) << 16; return cv.f;
}
static __device__ __forceinline__ unsigned short f2us(float f) {
    __hip_bfloat16 b = __float2bfloat16(f);
    union { __hip_bfloat16 b; unsigned short u; } cv; cv.b = b; return cv.u;
}
static __device__ __forceinline__ float elu_fast(float v) {
    return v > 0.f ? v : (__expf(v) - 1.0f);
}

// ---------------- prep: Cmat = inv(I - A^T); M = A^T*Cmat; Wcomb = fold(M, W_mean); AT = A^T ----
__global__ __launch_bounds__(256) void k_prep(const float* __restrict__ A,
                                              const float* __restrict__ Wm,
                                              float* __restrict__ Wcomb,
                                              float* __restrict__ AT) {
    __shared__ float Af[32][32];
    __shared__ float aug[32][65];
    __shared__ float Cm[32][32];
    __shared__ float Mm[32][32];
    __shared__ float fac[32];
    __shared__ float pivinv_s;
    int tid = threadIdx.x;
    for (int i = tid; i < 1024; i += 256) Af[i >> 5][i & 31] = A[i];
    __syncthreads();
    for (int i = tid; i < 2048; i += 256) {
        int r = i >> 6, c = i & 63;
        float v;
        if (c < 32) v = (r == c ? 1.0f : 0.0f) - Af[c][r];
        else        v = ((c - 32) == r ? 1.0f : 0.0f);
        aug[r][c] = v;
    }
    __syncthreads();
    for (int k = 0; k < 32; ++k) {
        if (tid == 0) pivinv_s = 1.0f / aug[k][k];
        __syncthreads();
        float pivinv = pivinv_s;
        if (tid < 64) aug[k][tid] *= pivinv;
        __syncthreads();
        if (tid < 32) fac[tid] = aug[tid][k];
        __syncthreads();
        for (int i = tid; i < 2048; i += 256) {
            int r = i >> 6, c = i & 63;
            if (r != k) aug[r][c] -= fac[r] * aug[k][c];
        }
        __syncthreads();
    }
    for (int i = tid; i < 1024; i += 256) Cm[i >> 5][i & 31] = aug[i >> 5][32 + (i & 31)];
    __syncthreads();
    for (int i = tid; i < 1024; i += 256) {
        int c = i >> 5, j = i & 31;
        float s = 0.f;
        for (int k = 0; k < 32; ++k) s += Af[k][c] * Cm[k][j];
        Mm[c][j] = s;
        AT[i] = Af[j][c];
    }
    __syncthreads();
    for (int i = tid; i < 16384; i += 256) {
        int h = i >> 7, m = i & 127;
        int c = m >> 2, d = m & 3;
        float s = 0.f;
        for (int j = 0; j < 32; ++j) s += Mm[c][j] * Wm[h * 128 + j * 4 + d];
        Wcomb[i] = s;
    }
}

// ---------------- CSR build: histogram -> multi-block scan -> scatter ------------------------
__global__ __launch_bounds__(256) void k_hist(const int* __restrict__ edst,
                                              unsigned int* __restrict__ deg) {
    int e = blockIdx.x * 256 + threadIdx.x;
    atomicAdd(&deg[edst[e]], 1u);
}

// scanA: 98 blocks x (256 threads x 4 elems) over padded 100352; within-block exclusive prefix
__global__ __launch_bounds__(256) void k_scanA(const unsigned int* __restrict__ deg,
                                               unsigned int* __restrict__ row_start,
                                               unsigned int* __restrict__ blk_sums) {
    __shared__ unsigned int sums[256];
    int tid = threadIdx.x;
    int gid = blockIdx.x * 256 + tid;
    uint4 d = ((const uint4*)deg)[gid];
    unsigned int p1 = d.x, p2 = d.x + d.y, p3 = p2 + d.z;
    unsigned int tsum = p3 + d.w;
    sums[tid] = tsum;
    __syncthreads();
    for (int off = 1; off < 256; off <<= 1) {
        unsigned int v = (tid >= off) ? sums[tid - off] : 0u;
        __syncthreads();
        sums[tid] += v;
        __syncthreads();
    }
    unsigned int excl = sums[tid] - tsum;
    int eb = gid * 4;
    if (eb + 0 < N_NODES) row_start[eb + 0] = excl;
    if (eb + 1 < N_NODES) row_start[eb + 1] = excl + p1;
    if (eb + 2 < N_NODES) row_start[eb + 2] = excl + p2;
    if (eb + 3 < N_NODES) row_start[eb + 3] = excl + p3;
    if (tid == 255) blk_sums[blockIdx.x] = sums[255];
}

// scanB: single small block scans the 98 block sums (in-place -> exclusive offsets)
__global__ __launch_bounds__(128) void k_scanB(unsigned int* __restrict__ blk_sums) {
    __shared__ unsigned int s[128];
    int tid = threadIdx.x;
    unsigned int v = (tid < 98) ? blk_sums[tid] : 0u;
    s[tid] = v;
    __syncthreads();
    for (int off = 1; off < 128; off <<= 1) {
        unsigned int x = (tid >= off) ? s[tid - off] : 0u;
        __syncthreads();
        s[tid] += x;
        __syncthreads();
    }
    if (tid < 98) blk_sums[tid] = s[tid] - v;
}

// scanC: add block offsets; fill cursor; set sentinel
__global__ __launch_bounds__(256) void k_scanC(unsigned int* __restrict__ row_start,
                                               unsigned int* __restrict__ cursor,
                                               const unsigned int* __restrict__ blk_sums) {
    int tid = threadIdx.x;
    unsigned int off = blk_sums[blockIdx.x];
    int eb = (blockIdx.x * 256 + tid) * 4;
    #pragma unroll
    for (int k = 0; k < 4; ++k) {
        int idx = eb + k;
        if (idx < N_NODES) {
            unsigned int u = row_start[idx] + off;
            row_start[idx] = u;
            cursor[idx] = u;
        }
    }
    if (blockIdx.x == 0 && tid == 0) row_start[N_NODES] = N_EDGES;
}

__global__ __launch_bounds__(256) void k_scatter(const int* __restrict__ esrc,
                                                 const int* __restrict__ edst,
                                                 const float* __restrict__ evalv,
                                                 unsigned int* __restrict__ cursor,
                                                 int* __restrict__ src_sorted,
                                                 float* __restrict__ val_sorted) {
    int e = blockIdx.x * 256 + threadIdx.x;
    unsigned int p = atomicAdd(&cursor[edst[e]], 1u);
    src_sorted[p] = esrc[e];
    val_sorted[p] = evalv[e];
}

// ---------------- gather1: S1[n][c] = sum_e val*X[src][c]  (no LDS, unroll x4) ---------------
__global__ __launch_bounds__(256) void k_gather1(const unsigned int* __restrict__ row_start,
                                                 const int* __restrict__ src_sorted,
                                                 const float* __restrict__ val_sorted,
                                                 const float* __restrict__ X,
                                                 float* __restrict__ S1) {
    int lane = threadIdx.x & 31;
    int n = blockIdx.x * 8 + (threadIdx.x >> 5);
    unsigned int i = row_start[n], e = row_start[n + 1];
    float a0 = 0.f, a1 = 0.f, a2 = 0.f, a3 = 0.f;
    for (; i + 4 <= e; i += 4) {
        int sa = src_sorted[i + 0], sb = src_sorted[i + 1];
        int sc = src_sorted[i + 2], sd = src_sorted[i + 3];
        float va = val_sorted[i + 0], vb = val_sorted[i + 1];
        float vc = val_sorted[i + 2], vd = val_sorted[i + 3];
        float xa = X[(size_t)sa * 32 + lane];
        float xb = X[(size_t)sb * 32 + lane];
        float xc = X[(size_t)sc * 32 + lane];
        float xd = X[(size_t)sd * 32 + lane];
        a0 += va * xa; a1 += vb * xb; a2 += vc * xc; a3 += vd * xd;
    }
    for (; i < e; ++i) a0 += val_sorted[i] * X[(size_t)src_sorted[i] * 32 + lane];
    S1[(size_t)n * 32 + lane] = (a0 + a1) + (a2 + a3);
}

// ---------------- gemm1: hidden = bf16(relu(S1 @ W_base)), [32 rows x 128 cols]/block --------
__global__ __launch_bounds__(256) void k_gemm1(const float* __restrict__ S1,
                                               const float* __restrict__ Wb,
                                               unsigned short* __restrict__ hidden) {
    __shared__ float Wb_s[4096];      // [k][j] 32x128 (16 KB)
    __shared__ float S1s[32 * 36];    // padded (4.6 KB)
    int tid = threadIdx.x;
    int n0 = blockIdx.x * 32;
    for (int i = tid; i < 1024; i += 256)
        ((float4*)Wb_s)[i] = ((const float4*)Wb)[i];
    for (int i = tid; i < 256; i += 256) ; // (no-op keeps structure clear)
    {
        int r = tid >> 3, cq = tid & 7;   // 32 rows x 8 quads
        *(float4*)&S1s[r * 36 + cq * 4] = *(const float4*)&S1[(size_t)(n0 + r) * 32 + cq * 4];
    }
    __syncthreads();
    int q = (tid & 31) * 4;               // col quad
    int r0 = tid >> 5;                    // 0..7 -> rows r0, r0+8, r0+16, r0+24
    float4 acc[4];
    #pragma unroll
    for (int i = 0; i < 4; ++i) acc[i] = make_float4(0.f, 0.f, 0.f, 0.f);
    for (int k4 = 0; k4 < 32; k4 += 4) {
        float4 s[4];
        #pragma unroll
        for (int i = 0; i < 4; ++i) s[i] = *(const float4*)&S1s[(r0 + i * 8) * 36 + k4];
        #pragma unroll
        for (int kk = 0; kk < 4; ++kk) {
            float4 w = *(const float4*)&Wb_s[(k4 + kk) * 128 + q];
            #pragma unroll
            for (int i = 0; i < 4; ++i) {
                float v = (&s[i].x)[kk];
                acc[i].x += v * w.x; acc[i].y += v * w.y;
                acc[i].z += v * w.z; acc[i].w += v * w.w;
            }
        }
    }
    #pragma unroll
    for (int i = 0; i < 4; ++i) {
        ushort4 o;
        o.x = f2us(fmaxf(acc[i].x, 0.f)); o.y = f2us(fmaxf(acc[i].y, 0.f));
        o.z = f2us(fmaxf(acc[i].z, 0.f)); o.w = f2us(fmaxf(acc[i].w, 0.f));
        *(ushort4*)&hidden[(size_t)(n0 + r0 + i * 8) * 128 + q] = o;
    }
}

// ---------------- gather2: S2[n][0:128] (bf16) = sum_e val*hidden[src]  (no LDS, unroll x4) ---
__global__ __launch_bounds__(256) void k_gather2(const unsigned int* __restrict__ row_start,
                                                 const int* __restrict__ src_sorted,
                                                 const float* __restrict__ val_sorted,
                                                 const unsigned short* __restrict__ hidden,
                                                 unsigned short* __restrict__ S2) {
    int lane = threadIdx.x & 31;
    int n = blockIdx.x * 8 + (threadIdx.x >> 5);
    unsigned int i = row_start[n], e = row_start[n + 1];
    float4 A0 = {0, 0, 0, 0}, A1 = {0, 0, 0, 0}, A2 = {0, 0, 0, 0}, A3 = {0, 0, 0, 0};
    for (; i + 4 <= e; i += 4) {
        int sa = src_sorted[i + 0], sb = src_sorted[i + 1];
        int sc = src_sorted[i + 2], sd = src_sorted[i + 3];
        float va = val_sorted[i + 0], vb = val_sorted[i + 1];
        float vc = val_sorted[i + 2], vd = val_sorted[i + 3];
        ushort4 ha = *(const ushort4*)&hidden[(size_t)sa * 128 + lane * 4];
        ushort4 hb = *(const ushort4*)&hidden[(size_t)sb * 128 + lane * 4];
        ushort4 hc = *(const ushort4*)&hidden[(size_t)sc * 128 + lane * 4];
        ushort4 hd = *(const ushort4*)&hidden[(size_t)sd * 128 + lane * 4];
        A0.x += va * us2f(ha.x); A0.y += va * us2f(ha.y); A0.z += va * us2f(ha.z); A0.w += va * us2f(ha.w);
        A1.x += vb * us2f(hb.x); A1.y += vb * us2f(hb.y); A1.z += vb * us2f(hb.z); A1.w += vb * us2f(hb.w);
        A2.x += vc * us2f(hc.x); A2.y += vc * us2f(hc.y); A2.z += vc * us2f(hc.z); A2.w += vc * us2f(hc.w);
        A3.x += vd * us2f(hd.x); A3.y += vd * us2f(hd.y); A3.z += vd * us2f(hd.z); A3.w += vd * us2f(hd.w);
    }
    for (; i < e; ++i) {
        float v = val_sorted[i];
        ushort4 h = *(const ushort4*)&hidden[(size_t)src_sorted[i] * 128 + lane * 4];
        A0.x += v * us2f(h.x); A0.y += v * us2f(h.y); A0.z += v * us2f(h.z); A0.w += v * us2f(h.w);
    }
    float4 acc;
    acc.x = (A0.x + A1.x) + (A2.x + A3.x);
    acc.y = (A0.y + A1.y) + (A2.y + A3.y);
    acc.z = (A0.z + A1.z) + (A2.z + A3.z);
    acc.w = (A0.w + A1.w) + (A2.w + A3.w);
    ushort4 o;
    o.x = f2us(acc.x); o.y = f2us(acc.y); o.z = f2us(acc.z); o.w = f2us(acc.w);
    *(ushort4*)&S2[(size_t)n * 128 + lane * 4] = o;
}

// ---------------- gemm2: masked_T = (S2 @ Wcomb)^T, [32 rows x 64 cols]/block ----------------
__global__ __launch_bounds__(256) void k_gemm2(const unsigned short* __restrict__ S2,
                                               const float* __restrict__ Wc,
                                               unsigned short* __restrict__ masked_T) {
    __shared__ float Wc_s[128 * 64];          // 32 KB col tile
    __shared__ float S2s[32 * 132];           // 16.9 KB
    __shared__ unsigned short Tt[64 * 40];    // 5 KB transpose tile (pad 40)
    int tid = threadIdx.x;
    int rb = blockIdx.x >> 1;
    int j0 = (blockIdx.x & 1) * 64;
    int n0 = rb * 32;
    for (int idx = tid; idx < 2048; idx += 256) {
        int k = idx >> 4, jq = idx & 15;
        *(float4*)&Wc_s[k * 64 + jq * 4] = *(const float4*)&Wc[k * 128 + j0 + jq * 4];
    }
    for (int idx = tid; idx < 1024; idx += 256) {
        int r = idx >> 5, kq = idx & 31;
        ushort4 h = *(const ushort4*)&S2[(size_t)(n0 + r) * 128 + kq * 4];
        float4 f = {us2f(h.x), us2f(h.y), us2f(h.z), us2f(h.w)};
        *(float4*)&S2s[r * 132 + kq * 4] = f;
    }
    __syncthreads();
    int q = (tid & 15) * 4;     // col quad within 64
    int r0 = tid >> 4;          // 0..15 -> rows r0, r0+16
    float4 a0 = {0, 0, 0, 0}, a1 = {0, 0, 0, 0};
    for (int k4 = 0; k4 < 128; k4 += 4) {
        float4 s0 = *(const float4*)&S2s[r0 * 132 + k4];
        float4 s1 = *(const float4*)&S2s[(r0 + 16) * 132 + k4];
        #pragma unroll
        for (int kk = 0; kk < 4; ++kk) {
            float v0 = (&s0.x)[kk];
            float v1 = (&s1.x)[kk];
            float4 w = *(const float4*)&Wc_s[(k4 + kk) * 64 + q];
            a0.x += v0 * w.x; a0.y += v0 * w.y; a0.z += v0 * w.z; a0.w += v0 * w.w;
            a1.x += v1 * w.x; a1.y += v1 * w.y; a1.z += v1 * w.z; a1.w += v1 * w.w;
        }
    }
    #pragma unroll
    for (int c = 0; c < 4; ++c) {
        Tt[(q + c) * 40 + r0]      = f2us((&a0.x)[c]);
        Tt[(q + c) * 40 + r0 + 16] = f2us((&a1.x)[c]);
    }
    __syncthreads();
    int j = tid >> 2, seg = tid & 3;    // 64 cols x 4 segs of 8 nodes
    uint4 pk = *(const uint4*)&Tt[j * 40 + seg * 8];
    *(uint4*)&masked_T[(size_t)(j0 + j) * N_NODES + n0 + seg * 8] = pk;
}

// ---------------- noise head: rec_noise = sqrt(lambda) * (noise @ Wrec) ----------------------
__global__ __launch_bounds__(256) void k_noise(const float* __restrict__ noise,
                                               const float* __restrict__ Wrec,
                                               float* __restrict__ rec_noise) {
    __shared__ float Wr[4096];        // [k][o] 128x32
    __shared__ float Ns[64 * 132];
    int tid = threadIdx.x;
    int n0 = blockIdx.x * 64;
    for (int i = tid; i < 1024; i += 256)
        ((float4*)Wr)[i] = ((const float4*)Wrec)[i];
    for (int i = tid; i < 2048; i += 256) {
        int row = i >> 5, c4 = i & 31;
        int n = n0 + row;
        float4 v = (n < N_NODES) ? ((const float4*)(noise + (size_t)n * 128))[c4]
                                 : make_float4(0.f, 0.f, 0.f, 0.f);
        *(float4*)&Ns[row * 132 + c4 * 4] = v;
    }
    __syncthreads();
    int r = tid >> 2, q = (tid & 3) * 8;
    float4 acc0 = {0, 0, 0, 0}, acc1 = {0, 0, 0, 0};
    for (int k = 0; k < 128; ++k) {
        float nv = Ns[r * 132 + k];
        float4 w0 = *(const float4*)&Wr[k * 32 + q];
        float4 w1 = *(const float4*)&Wr[k * 32 + q + 4];
        acc0.x += nv * w0.x; acc0.y += nv * w0.y; acc0.z += nv * w0.z; acc0.w += nv * w0.w;
        acc1.x += nv * w1.x; acc1.y += nv * w1.y; acc1.z += nv * w1.z; acc1.w += nv * w1.w;
    }
    const float SQ = 0.03162277660168379f;
    acc0.x *= SQ; acc0.y *= SQ; acc0.z *= SQ; acc0.w *= SQ;
    acc1.x *= SQ; acc1.y *= SQ; acc1.z *= SQ; acc1.w *= SQ;
    int n = n0 + r;
    if (n < N_NODES) {
        ((float4*)(rec_noise + (size_t)n * 32 + q))[0] = acc0;
        ((float4*)(rec_noise + (size_t)n * 32 + q + 4))[0] = acc1;
    }
}

// ---------------- nodez: per-lane node MLP + rec_x head --------------------------------------
__global__ __launch_bounds__(256) void k_nodez(const unsigned short* __restrict__ masked_T,
                                               const float* __restrict__ rec_noise,
                                               const float* __restrict__ Wz1,
                                               const float* __restrict__ bz1,
                                               const float* __restrict__ Wz2,
                                               const float* __restrict__ bz2,
                                               const float* __restrict__ Wrec,
                                               const float* __restrict__ brec,
                                               float* __restrict__ out) {
    __shared__ float Wz1s[4096];
    __shared__ float Wz2s[4096];
    __shared__ float Wrecs[4096];
    __shared__ float bz1s[1024];
    __shared__ float bz2s[128];
    __shared__ float brecs[32];
    int tid = threadIdx.x;
    for (int i = tid; i < 4096; i += 256) {
        Wz1s[i] = Wz1[i];
        Wz2s[i] = Wz2[i];
        Wrecs[i] = Wrec[i];
    }
    for (int i = tid; i < 1024; i += 256) bz1s[i] = bz1[i];
    if (tid < 128) bz2s[tid] = bz2[tid];
    if (tid < 32) brecs[tid] = brec[tid];
    __syncthreads();

    int n = blockIdx.x * 256 + tid;
    bool ok = n < N_NODES;
    int nn = ok ? n : (N_NODES - 1);

    float rec[32];
    #pragma unroll
    for (int q = 0; q < 8; ++q) {
        float4 rv = ((const float4*)(rec_noise + (size_t)nn * 32))[q];
        rec[q * 4 + 0] = brecs[q * 4 + 0] + rv.x;
        rec[q * 4 + 1] = brecs[q * 4 + 1] + rv.y;
        rec[q * 4 + 2] = brecs[q * 4 + 2] + rv.z;
        rec[q * 4 + 3] = brecs[q * 4 + 3] + rv.w;
    }

    for (int c = 0; c < 32; ++c) {
        float m0 = us2f(masked_T[(size_t)(c * 4 + 0) * N_NODES + nn]);
        float m1 = us2f(masked_T[(size_t)(c * 4 + 1) * N_NODES + nn]);
        float m2 = us2f(masked_T[(size_t)(c * 4 + 2) * N_NODES + nn]);
        float m3 = us2f(masked_T[(size_t)(c * 4 + 3) * N_NODES + nn]);
        float z0 = bz2s[c * 4 + 0], z1 = bz2s[c * 4 + 1];
        float z2 = bz2s[c * 4 + 2], z3 = bz2s[c * 4 + 3];
        #pragma unroll
        for (int g = 0; g < 32; ++g) {
            float v = bz1s[c * 32 + g]
                    + m0 * Wz1s[c * 128 + g]
                    + m1 * Wz1s[c * 128 + 32 + g]
                    + m2 * Wz1s[c * 128 + 64 + g]
                    + m3 * Wz1s[c * 128 + 96 + g];
            v = elu_fast(v);
            z0 += v * Wz2s[c * 128 + g * 4 + 0];
            z1 += v * Wz2s[c * 128 + g * 4 + 1];
            z2 += v * Wz2s[c * 128 + g * 4 + 2];
            z3 += v * Wz2s[c * 128 + g * 4 + 3];
        }
        #pragma unroll
        for (int o = 0; o < 32; ++o) {
            rec[o] += z0 * Wrecs[(c * 4 + 0) * 32 + o]
                    + z1 * Wrecs[(c * 4 + 1) * 32 + o]
                    + z2 * Wrecs[(c * 4 + 2) * 32 + o]
                    + z3 * Wrecs[(c * 4 + 3) * 32 + o];
        }
    }
    if (ok) {
        #pragma unroll
        for (int q = 0; q < 8; ++q) {
            float4 v = {rec[q * 4 + 0], rec[q * 4 + 1], rec[q * 4 + 2], rec[q * 4 + 3]};
            ((float4*)(out + (size_t)n * 32))[q] = v;
        }
    }
}

// ---------------- label head: pred = MLP_c(AT@label), one lane per node ----------------------
__global__ __launch_bounds__(256) void k_label(const float* __restrict__ label,
                                               const float* __restrict__ AT,
                                               const float* __restrict__ Wl1,
                                               const float* __restrict__ bl1,
                                               const float* __restrict__ Wl2,
                                               const float* __restrict__ bl2,
                                               float* __restrict__ out) {
    __shared__ float ATs[1024], Wl1s[1024], bl1s[1024], Wl2s[1024], bl2s[32];
    int tid = threadIdx.x;
    for (int i = tid; i < 1024; i += 256) {
        ATs[i] = AT[i];
        Wl1s[i] = Wl1[i];
        bl1s[i] = bl1[i];
        Wl2s[i] = Wl2[i];
    }
    if (tid < 32) bl2s[tid] = bl2[tid];
    __syncthreads();

    int n = blockIdx.x * 256 + tid;
    bool ok = n < N_NODES;
    int nn = ok ? n : (N_NODES - 1);

    float lab[32];
    #pragma unroll
    for (int q = 0; q < 8; ++q) {
        float4 lv = ((const float4*)(label + (size_t)nn * 32))[q];
        lab[q * 4 + 0] = lv.x; lab[q * 4 + 1] = lv.y;
        lab[q * 4 + 2] = lv.z; lab[q * 4 + 3] = lv.w;
    }
    float pred[32];
    for (int c = 0; c < 32; ++c) {
        float ml = 0.f;
        #pragma unroll
        for (int k = 0; k < 32; ++k) ml += ATs[c * 32 + k] * lab[k];
        float p = bl2s[c];
        #pragma unroll
        for (int g = 0; g < 32; ++g) {
            float h = elu_fast(ml * Wl1s[c * 32 + g] + bl1s[c * 32 + g]);
            p += h * Wl2s[c * 32 + g];
        }
        pred[c] = p;
    }
    if (ok) {
        #pragma unroll
        for (int q = 0; q < 8; ++q) {
            float4 v = {pred[q * 4 + 0], pred[q * 4 + 1], pred[q * 4 + 2], pred[q * 4 + 3]};
            ((float4*)(out + (size_t)N_NODES * 32 + (size_t)n * 32))[q] = v;
        }
    }
}

extern "C" void kernel_launch(void* const* d_in, const int* in_sizes, int n_in,
                              void* d_out, int out_size, void* d_ws, size_t ws_size,
                              hipStream_t stream) {
    const float* X      = (const float*)d_in[0];
    const float* label  = (const float*)d_in[1];
    const float* evalv  = (const float*)d_in[2];
    const float* noise  = (const float*)d_in[3];
    const float* W_base = (const float*)d_in[4];
    const float* W_mean = (const float*)d_in[5];
    // d_in[6] = W_logstd : dead code in the reference
    const float* A      = (const float*)d_in[7];
    const float* Wz1    = (const float*)d_in[8];
    const float* bz1    = (const float*)d_in[9];
    const float* Wz2    = (const float*)d_in[10];
    const float* bz2    = (const float*)d_in[11];
    const float* Wl1    = (const float*)d_in[12];
    const float* bl1    = (const float*)d_in[13];
    const float* Wl2    = (const float*)d_in[14];
    const float* bl2    = (const float*)d_in[15];
    const float* Wrec   = (const float*)d_in[16];
    const float* brec   = (const float*)d_in[17];
    const int* esrc = (const int*)d_in[18];
    const int* edst = (const int*)d_in[19];
    float* out = (float*)d_out;

    char* ws = (char*)d_ws;
    // Layout (~62.3 MB total; <= proven-safe 73.3 MB):
    float*          Wcomb      = (float*)(ws);                        // @0        64 KB
    float*          AT         = (float*)(ws + 65536);                // @65536    4 KB
    unsigned int*   blk_sums   = (unsigned int*)(ws + 69632);         // @69632    1 KB (98 used)
    unsigned int*   deg        = (unsigned int*)(ws + 70656);         // @70656    padded 100352 u32
    unsigned int*   row_start  = (unsigned int*)(ws + 472064);        // @472064   N+1 u32
    unsigned int*   cursor     = (unsigned int*)(ws + 873984);        // @873984   N u32
    int*            src_sorted = (int*)(ws + 1273984);                // 6.4 MB
    float*          val_sorted = (float*)(ws + 7673984);              // 6.4 MB
    // slot A (25.6 MB): hidden (bf16) -> masked_T (bf16, transposed)
    unsigned short* hidden     = (unsigned short*)(ws + 14073984);
    unsigned short* masked_T   = (unsigned short*)(ws + 14073984);
    // slot B (25.6 MB): S1 (f32, 12.8 MB) -> S2 (bf16, 25.6 MB) -> rec_noise (f32, 12.8 MB)
    float*          S1         = (float*)(ws + 39673984);
    unsigned short* S2         = (unsigned short*)(ws + 39673984);
    float*          rec_noise  = (float*)(ws + 39673984);

    hipMemsetAsync(deg, 0, 100352 * sizeof(unsigned int), stream);
    k_prep<<<1, 256, 0, stream>>>(A, W_mean, Wcomb, AT);
    k_hist<<<N_EDGES / 256, 256, 0, stream>>>(edst, deg);
    k_scanA<<<98, 256, 0, stream>>>(deg, row_start, blk_sums);
    k_scanB<<<1, 128, 0, stream>>>(blk_sums);
    k_scanC<<<98, 256, 0, stream>>>(row_start, cursor, blk_sums);
    k_scatter<<<N_EDGES / 256, 256, 0, stream>>>(esrc, edst, evalv, cursor, src_sorted, val_sorted);
    k_gather1<<<N_NODES / 8, 256, 0, stream>>>(row_start, src_sorted, val_sorted, X, S1);
    k_gemm1<<<N_NODES / 32, 256, 0, stream>>>(S1, W_base, hidden);
    k_gather2<<<N_NODES / 8, 256, 0, stream>>>(row_start, src_sorted, val_sorted, hidden, S2);
    k_gemm2<<<(N_NODES / 32) * 2, 256, 0, stream>>>(S2, Wcomb, masked_T);
    k_noise<<<(N_NODES + 63) / 64, 256, 0, stream>>>(noise, Wrec, rec_noise);
    k_nodez<<<(N_NODES + 255) / 256, 256, 0, stream>>>(masked_T, rec_noise,
                                                       Wz1, bz1, Wz2, bz2, Wrec, brec, out);
    k_label<<<(N_NODES + 255) / 256, 256, 0, stream>>>(label, AT, Wl1, bl1, Wl2, bl2, out);
}